// Round 4
// baseline (7644.378 us; speedup 1.0000x reference)
//
#include <hip/hip_runtime.h>
#include <hip/hip_bf16.h>
#include <cstdint>

#define BATCH 65536
#define EXPERTS 8
#define IN_DIM 512
#define OUT_DIM 512

typedef short bf16x8 __attribute__((ext_vector_type(8)));
typedef float f32x4 __attribute__((ext_vector_type(4)));

__device__ __forceinline__ unsigned short f2bf_rne(float f) {
  unsigned u = __float_as_uint(f);
  u += 0x7FFFu + ((u >> 16) & 1u);   // round-to-nearest-even (inputs finite)
  return (unsigned short)(u >> 16);
}
__device__ __forceinline__ float bf2f(unsigned short h) {
  return __uint_as_float(((unsigned)h) << 16);
}

// async global->LDS, 16B per lane; lds base must be wave-uniform (guide §5)
__device__ __forceinline__ void async_copy16(void* lds, const void* g) {
  __builtin_amdgcn_global_load_lds((const __attribute__((address_space(1))) void*)g,
                                   (__attribute__((address_space(3))) void*)lds, 16, 0, 0);
}

// ---- prep 1: W [E][I][O] f32 -> Wt_hi/Wt_lo [E][O][I] bf16 (split + transpose) ----
__global__ __launch_bounds__(256) void wsplit_kernel(const float* __restrict__ W,
                                                     unsigned short* __restrict__ Wth,
                                                     unsigned short* __restrict__ Wtl) {
  __shared__ float t[32][33];
  const int e = blockIdx.z;
  const int i0 = blockIdx.x * 32;
  const int o0 = blockIdx.y * 32;
  const int tx = threadIdx.x & 31, ty = threadIdx.x >> 5;  // 32x8
#pragma unroll
  for (int p = 0; p < 4; ++p)
    t[ty + p * 8][tx] = W[(size_t)(e * IN_DIM + i0 + ty + p * 8) * OUT_DIM + o0 + tx];
  __syncthreads();
#pragma unroll
  for (int p = 0; p < 4; ++p) {
    float v = t[tx][ty + p * 8];                 // v = W[e][i0+tx][o0+ty+p*8]
    unsigned short hi = f2bf_rne(v);
    unsigned short lo = f2bf_rne(v - bf2f(hi));
    size_t idx = (size_t)(e * OUT_DIM + o0 + ty + p * 8) * IN_DIM + i0 + tx;
    Wth[idx] = hi;
    Wtl[idx] = lo;
  }
}

// ---- prep 2: x [B][I] f32 -> Xh/Xl bf16 ----
__global__ __launch_bounds__(256) void xsplit_kernel(const float* __restrict__ x,
                                                     unsigned short* __restrict__ Xh,
                                                     unsigned short* __restrict__ Xl) {
  const size_t i4 = (size_t)blockIdx.x * 256 + threadIdx.x;
  const float4 v = ((const float4*)x)[i4];
  ushort4 h, l;
  h.x = f2bf_rne(v.x); l.x = f2bf_rne(v.x - bf2f(h.x));
  h.y = f2bf_rne(v.y); l.y = f2bf_rne(v.y - bf2f(h.y));
  h.z = f2bf_rne(v.z); l.z = f2bf_rne(v.z - bf2f(h.z));
  h.w = f2bf_rne(v.w); l.w = f2bf_rne(v.w - bf2f(h.w));
  ((ushort4*)Xh)[i4] = h;
  ((ushort4*)Xl)[i4] = l;
}

// ---- main GEMM: 128x128 tile, BK=32, 4 waves (2x2), expert-INNER gated-partial
//      accumulation; B ping-pong pipeline; A single-buffer time-shifted prefetch;
//      XOR bank swizzle (linear LDS dest + inverse-swizzled global src + swz read) ----
__global__ __launch_bounds__(256, 2) void moe_gemm_kernel(
    const unsigned short* __restrict__ Xh, const unsigned short* __restrict__ Xl,
    const unsigned short* __restrict__ Wth, const unsigned short* __restrict__ Wtl,
    const float* __restrict__ gates,   // [B][E]
    const float* __restrict__ bias,    // [E][O]
    float* __restrict__ out) {         // [B][O]
  __shared__ __align__(16) unsigned short sAh[128 * 32], sAl[128 * 32];     // 16 KB
  __shared__ __align__(16) unsigned short sBh[2][128 * 32], sBl[2][128 * 32]; // 32 KB
  __shared__ __align__(16) float sGateT[EXPERTS * 128];                     // 4 KB

  const int tid = threadIdx.x;
  const int lane = tid & 63;
  const int wid = tid >> 6;
  const int wr = wid >> 1, wc = wid & 1;
  const int l15 = lane & 15, l4 = lane >> 4;

  const int brow = blockIdx.x * 128;   // batch tile (512 tiles, fast dim)
  const int bcol = blockIdx.y * 128;   // output-feature tile (4 tiles, slow dim)

  // gates -> LDS transposed [e][row] for vector (float4) reads in the fold
  {
    const int r = tid >> 1, q = (tid & 1) * 4;
    float4 g4 = *(const float4*)(gates + (size_t)(brow + r) * EXPERTS + q);
    sGateT[(q + 0) * 128 + r] = g4.x;
    sGateT[(q + 1) * 128 + r] = g4.y;
    sGateT[(q + 2) * 128 + r] = g4.z;
    sGateT[(q + 3) * 128 + r] = g4.w;
  }

  // staging geometry: thread t -> LDS row srow, stored 16B-slot (t&3); the
  // GLOBAL chunk it fetches is XOR-swizzled so ds_reads below are 2-way max.
  const int srow = tid >> 2;                                   // 0..63
  const int csel = ((tid & 3) ^ ((srow >> 1) & 3)) * 8;        // element offset
  const unsigned short* gAh = Xh + (size_t)(brow + srow) * IN_DIM + csel;
  const unsigned short* gAl = Xl + (size_t)(brow + srow) * IN_DIM + csel;
  const unsigned short* gBh = Wth + (size_t)(bcol + srow) * IN_DIM + csel;
  const unsigned short* gBl = Wtl + (size_t)(bcol + srow) * IN_DIM + csel;
  const int wb = wid * 1024;  // per-wave byte base within an 8KB plane

#define STAGE_A(kk)                                                      \
  do {                                                                   \
    async_copy16((char*)sAh + wb,        gAh + (kk));                    \
    async_copy16((char*)sAh + 4096 + wb, gAh + (kk) + 64 * IN_DIM);      \
    async_copy16((char*)sAl + wb,        gAl + (kk));                    \
    async_copy16((char*)sAl + 4096 + wb, gAl + (kk) + 64 * IN_DIM);      \
  } while (0)

#define STAGE_B(e, kk, buf)                                                        \
  do {                                                                             \
    const size_t eo = (size_t)(e) * OUT_DIM * IN_DIM;                              \
    async_copy16((char*)sBh[buf] + wb,        gBh + eo + (kk));                    \
    async_copy16((char*)sBh[buf] + 4096 + wb, gBh + eo + (kk) + 64 * IN_DIM);      \
    async_copy16((char*)sBl[buf] + wb,        gBl + eo + (kk));                    \
    async_copy16((char*)sBl[buf] + 4096 + wb, gBl + eo + (kk) + 64 * IN_DIM);      \
  } while (0)

  // swizzled fragment read offsets (elements): slot = l4 ^ ((row>>1)&3)
  int aoff[4], boff[4];
#pragma unroll
  for (int m = 0; m < 4; ++m) {
    const int row = wr * 64 + m * 16 + l15;
    aoff[m] = row * 32 + ((l4 ^ ((l15 >> 1) & 3)) * 8);
  }
#pragma unroll
  for (int n = 0; n < 4; ++n) {
    const int row = wc * 64 + n * 16 + l15;
    boff[n] = row * 32 + ((l4 ^ ((l15 >> 1) & 3)) * 8);
  }

  f32x4 accY[4][4];
#pragma unroll
  for (int m = 0; m < 4; ++m)
#pragma unroll
    for (int n = 0; n < 4; ++n) accY[m][n] = (f32x4){0.f, 0.f, 0.f, 0.f};
  const f32x4 zero4 = (f32x4){0.f, 0.f, 0.f, 0.f};

  STAGE_A(0);
  STAGE_B(0, 0, 0);
  __syncthreads();   // drains vmcnt + covers sGateT writes

#pragma unroll 1
  for (int kk = 0; kk < IN_DIM; kk += 32) {
    // A fragments for this k-step, hoisted across all 8 expert phases
    bf16x8 ah[4], al[4];
#pragma unroll
    for (int m = 0; m < 4; ++m) {
      ah[m] = *(const bf16x8*)(sAh + aoff[m]);
      al[m] = *(const bf16x8*)(sAl + aoff[m]);
    }

#pragma unroll
    for (int e = 0; e < EXPERTS; ++e) {
      bf16x8 bh[4], bl[4];
#pragma unroll
      for (int n = 0; n < 4; ++n) {
        bh[n] = *(const bf16x8*)(sBh[e & 1] + boff[n]);
        bl[n] = *(const bf16x8*)(sBl[e & 1] + boff[n]);
      }

      // issue next-phase staging BEFORE compute (latency hides under MFMAs;
      // drained by this phase's end barrier)
      if (e < 7) {
        STAGE_B(e + 1, kk, (e + 1) & 1);
      } else if (kk + 32 < IN_DIM) {
        STAGE_B(0, kk + 32, 0);
      }
      // sA safe to overwrite after e==0's barrier (A-frags live in registers)
      if (e == 1 && kk + 32 < IN_DIM) STAGE_A(kk + 32);

      f32x4 p[4][4];
#pragma unroll
      for (int m = 0; m < 4; ++m)
#pragma unroll
        for (int n = 0; n < 4; ++n) {
          p[m][n] = __builtin_amdgcn_mfma_f32_16x16x32_bf16(ah[m], bh[n], zero4, 0, 0, 0);
          p[m][n] = __builtin_amdgcn_mfma_f32_16x16x32_bf16(al[m], bh[n], p[m][n], 0, 0, 0);
          p[m][n] = __builtin_amdgcn_mfma_f32_16x16x32_bf16(ah[m], bl[n], p[m][n], 0, 0, 0);
        }

      // gated fold of the k-partial into the running output accumulator
#pragma unroll
      for (int m = 0; m < 4; ++m) {
        const f32x4 gv = *(const f32x4*)(sGateT + e * 128 + wr * 64 + m * 16 + l4 * 4);
#pragma unroll
        for (int n = 0; n < 4; ++n)
#pragma unroll
          for (int j = 0; j < 4; ++j) accY[m][n][j] += gv[j] * p[m][n][j];
      }

      __syncthreads();  // WAR/RAW fence for the ping-pong buffers + vmcnt drain
    }
  }

  // epilogue: y += sum_e g[row,e] * bias[e,col]; then store
#pragma unroll
  for (int e = 0; e < EXPERTS; ++e) {
    f32x4 gm[4];
#pragma unroll
    for (int m = 0; m < 4; ++m)
      gm[m] = *(const f32x4*)(sGateT + e * 128 + wr * 64 + m * 16 + l4 * 4);
#pragma unroll
    for (int n = 0; n < 4; ++n) {
      const float bb = bias[(size_t)e * OUT_DIM + bcol + wc * 64 + n * 16 + l15];
#pragma unroll
      for (int m = 0; m < 4; ++m)
#pragma unroll
        for (int j = 0; j < 4; ++j) accY[m][n][j] += gm[m][j] * bb;
    }
  }

#pragma unroll
  for (int m = 0; m < 4; ++m)
#pragma unroll
    for (int n = 0; n < 4; ++n) {
      const int row = brow + wr * 64 + m * 16 + l4 * 4;
      const int col = bcol + wc * 64 + n * 16 + l15;
#pragma unroll
      for (int j = 0; j < 4; ++j)
        out[(size_t)(row + j) * OUT_DIM + col] = accY[m][n][j];
    }
#undef STAGE_A
#undef STAGE_B
}

extern "C" void kernel_launch(void* const* d_in, const int* in_sizes, int n_in,
                              void* d_out, int out_size, void* d_ws, size_t ws_size,
                              hipStream_t stream) {
  const float* x     = (const float*)d_in[0];  // [B][I]
  const float* gates = (const float*)d_in[1];  // [B][E]
  const float* W     = (const float*)d_in[2];  // [E][I][O]
  const float* bias  = (const float*)d_in[3];  // [E][1][O]
  float* out = (float*)d_out;

  // workspace layout: Wt_hi(4MiB) | Wt_lo(4MiB) | Xh(64MiB) | Xl(64MiB) = 136MiB
  unsigned short* Wth = (unsigned short*)d_ws;
  unsigned short* Wtl = Wth + (size_t)EXPERTS * IN_DIM * OUT_DIM;
  unsigned short* Xh  = Wtl + (size_t)EXPERTS * IN_DIM * OUT_DIM;
  unsigned short* Xl  = Xh + (size_t)BATCH * IN_DIM;

  wsplit_kernel<<<dim3(16, 16, 8), 256, 0, stream>>>(W, Wth, Wtl);
  xsplit_kernel<<<dim3(BATCH * IN_DIM / 4 / 256), 256, 0, stream>>>(x, Xh, Xl);
  // x = row-tiles (fast) so a dispatch window works one col-slice -> W stays L2-resident
  moe_gemm_kernel<<<dim3(BATCH / 128, OUT_DIM / 128), 256, 0, stream>>>(
      Xh, Xl, Wth, Wtl, gates, bias, out);
}

// Round 5
// 1120.274 us; speedup vs baseline: 6.8237x; 6.8237x over previous
//
#include <hip/hip_runtime.h>
#include <hip/hip_bf16.h>
#include <cstdint>

#define BATCH 65536
#define EXPERTS 8
#define IN_DIM 512
#define OUT_DIM 512

typedef short bf16x8 __attribute__((ext_vector_type(8)));
typedef float f32x4 __attribute__((ext_vector_type(4)));

__device__ __forceinline__ unsigned short f2bf_rne(float f) {
  unsigned u = __float_as_uint(f);
  u += 0x7FFFu + ((u >> 16) & 1u);   // round-to-nearest-even (inputs finite)
  return (unsigned short)(u >> 16);
}
__device__ __forceinline__ float bf2f(unsigned short h) {
  return __uint_as_float(((unsigned)h) << 16);
}

// async global->LDS, 16B per lane; LDS dest is wave-uniform base + lane*16 (guide §5)
__device__ __forceinline__ void async_copy16(void* lds, const void* g) {
  __builtin_amdgcn_global_load_lds((const __attribute__((address_space(1))) void*)g,
                                   (__attribute__((address_space(3))) void*)lds, 16, 0, 0);
}

// ---- prep 1: W [E][I][O] f32 -> Wt_hi/Wt_lo [E][O][I] bf16 (split + transpose) ----
__global__ __launch_bounds__(256) void wsplit_kernel(const float* __restrict__ W,
                                                     unsigned short* __restrict__ Wth,
                                                     unsigned short* __restrict__ Wtl) {
  __shared__ float t[32][33];
  const int e = blockIdx.z;
  const int i0 = blockIdx.x * 32;
  const int o0 = blockIdx.y * 32;
  const int tx = threadIdx.x & 31, ty = threadIdx.x >> 5;  // 32x8
#pragma unroll
  for (int p = 0; p < 4; ++p)
    t[ty + p * 8][tx] = W[(size_t)(e * IN_DIM + i0 + ty + p * 8) * OUT_DIM + o0 + tx];
  __syncthreads();
#pragma unroll
  for (int p = 0; p < 4; ++p) {
    float v = t[tx][ty + p * 8];                 // v = W[e][i0+tx][o0+ty+p*8]
    unsigned short hi = f2bf_rne(v);
    unsigned short lo = f2bf_rne(v - bf2f(hi));
    size_t idx = (size_t)(e * OUT_DIM + o0 + ty + p * 8) * IN_DIM + i0 + tx;
    Wth[idx] = hi;
    Wtl[idx] = lo;
  }
}

// ---- prep 2: x [B][I] f32 -> Xh/Xl bf16 ----
__global__ __launch_bounds__(256) void xsplit_kernel(const float* __restrict__ x,
                                                     unsigned short* __restrict__ Xh,
                                                     unsigned short* __restrict__ Xl) {
  const size_t i4 = (size_t)blockIdx.x * 256 + threadIdx.x;
  const float4 v = ((const float4*)x)[i4];
  ushort4 h, l;
  h.x = f2bf_rne(v.x); l.x = f2bf_rne(v.x - bf2f(h.x));
  h.y = f2bf_rne(v.y); l.y = f2bf_rne(v.y - bf2f(h.y));
  h.z = f2bf_rne(v.z); l.z = f2bf_rne(v.z - bf2f(h.z));
  h.w = f2bf_rne(v.w); l.w = f2bf_rne(v.w - bf2f(h.w));
  ((ushort4*)Xh)[i4] = h;
  ((ushort4*)Xl)[i4] = l;
}

// ---- main GEMM: 128x128 tile, BK=32, 4 waves (2x2), 16x16x32 bf16 MFMA x3.
//      Expert-OUTER (accP is MFMA-chained only -> AGPRs, fold once per expert;
//      R4 lesson: VALU-touched accumulators spill).  k-level double-buffer with
//      ONE barrier per k-step, staging issued before the MFMA cluster.
//      Both-sides XOR swizzle (proven R4: conflicts 6.9e7 -> ~0). ----
__global__ __launch_bounds__(256, 2) void moe_gemm_kernel(
    const unsigned short* __restrict__ Xh, const unsigned short* __restrict__ Xl,
    const unsigned short* __restrict__ Wth, const unsigned short* __restrict__ Wtl,
    const float* __restrict__ gates,   // [B][E]
    const float* __restrict__ bias,    // [E][O]
    float* __restrict__ out) {         // [B][O]
  __shared__ __align__(16) unsigned short sAh[2][4096], sAl[2][4096];  // 32 KB
  __shared__ __align__(16) unsigned short sBh[2][4096], sBl[2][4096];  // 32 KB
  __shared__ __align__(16) float sGateT[EXPERTS * 128];                // 4 KB

  const int tid = threadIdx.x;
  const int lane = tid & 63;
  const int wid = tid >> 6;
  const int wr = wid >> 1, wc = wid & 1;
  const int l15 = lane & 15, l4 = lane >> 4;

  const int brow = blockIdx.x * 128;   // batch tile (512, fast dim)
  const int bcol = blockIdx.y * 128;   // output-feature tile (4, slow dim)

  // gates -> LDS transposed [e][row] for float4 reads in the per-expert fold
  {
    const int r = tid >> 1, q = (tid & 1) * 4;
    float4 g4 = *(const float4*)(gates + (size_t)(brow + r) * EXPERTS + q);
    sGateT[(q + 0) * 128 + r] = g4.x;
    sGateT[(q + 1) * 128 + r] = g4.y;
    sGateT[(q + 2) * 128 + r] = g4.z;
    sGateT[(q + 3) * 128 + r] = g4.w;
  }

  // staging geometry: thread t -> LDS row (t>>2), stored 16B-slot (t&3); the
  // GLOBAL chunk fetched is XOR-swizzled so ds_reads below are conflict-free.
  const int srow = tid >> 2;                                   // 0..63
  const int csel = ((tid & 3) ^ ((srow >> 1) & 3)) * 8;        // element offset
  const unsigned short* gAh = Xh + (size_t)(brow + srow) * IN_DIM + csel;
  const unsigned short* gAl = Xl + (size_t)(brow + srow) * IN_DIM + csel;
  const unsigned short* gBh = Wth + (size_t)(bcol + srow) * IN_DIM + csel;
  const unsigned short* gBl = Wtl + (size_t)(bcol + srow) * IN_DIM + csel;
  const int wb = wid * 1024;  // per-wave byte base within a 4KB half-plane

#define STAGE_A(kk, b)                                                     \
  do {                                                                     \
    async_copy16((char*)sAh[b] + wb,        gAh + (kk));                   \
    async_copy16((char*)sAh[b] + 4096 + wb, gAh + (kk) + 64 * IN_DIM);     \
    async_copy16((char*)sAl[b] + wb,        gAl + (kk));                   \
    async_copy16((char*)sAl[b] + 4096 + wb, gAl + (kk) + 64 * IN_DIM);     \
  } while (0)

#define STAGE_B(e, kk, b)                                                            \
  do {                                                                               \
    const size_t eo = (size_t)(e) * OUT_DIM * IN_DIM;                                \
    async_copy16((char*)sBh[b] + wb,        gBh + eo + (kk));                        \
    async_copy16((char*)sBh[b] + 4096 + wb, gBh + eo + (kk) + 64 * IN_DIM);          \
    async_copy16((char*)sBl[b] + wb,        gBl + eo + (kk));                        \
    async_copy16((char*)sBl[b] + 4096 + wb, gBl + eo + (kk) + 64 * IN_DIM);          \
  } while (0)

  // swizzled fragment read offsets (elements): slot = l4 ^ ((row>>1)&3)
  int aoff[4], boff[4];
#pragma unroll
  for (int m = 0; m < 4; ++m) {
    const int row = wr * 64 + m * 16 + l15;
    aoff[m] = row * 32 + ((l4 ^ ((l15 >> 1) & 3)) * 8);
  }
#pragma unroll
  for (int n = 0; n < 4; ++n) {
    const int row = wc * 64 + n * 16 + l15;
    boff[n] = row * 32 + ((l4 ^ ((l15 >> 1) & 3)) * 8);
  }

  f32x4 accY[4][4], accP[4][4];
#pragma unroll
  for (int m = 0; m < 4; ++m)
#pragma unroll
    for (int n = 0; n < 4; ++n) {
      accY[m][n] = (f32x4){0.f, 0.f, 0.f, 0.f};
      accP[m][n] = (f32x4){0.f, 0.f, 0.f, 0.f};
    }

  // one k-substep: compute on buffer `b`, having already issued next-stage
#define COMPUTE(b)                                                                   \
  do {                                                                               \
    bf16x8 ah[4], al[4], bh[4], bl[4];                                               \
    _Pragma("unroll") for (int m = 0; m < 4; ++m) {                                  \
      ah[m] = *(const bf16x8*)(&sAh[b][0] + aoff[m]);                                \
      al[m] = *(const bf16x8*)(&sAl[b][0] + aoff[m]);                                \
    }                                                                                \
    _Pragma("unroll") for (int n = 0; n < 4; ++n) {                                  \
      bh[n] = *(const bf16x8*)(&sBh[b][0] + boff[n]);                                \
      bl[n] = *(const bf16x8*)(&sBl[b][0] + boff[n]);                                \
    }                                                                                \
    _Pragma("unroll") for (int m = 0; m < 4; ++m)                                    \
      _Pragma("unroll") for (int n = 0; n < 4; ++n) {                                \
        accP[m][n] = __builtin_amdgcn_mfma_f32_16x16x32_bf16(ah[m], bh[n], accP[m][n], 0, 0, 0); \
        accP[m][n] = __builtin_amdgcn_mfma_f32_16x16x32_bf16(al[m], bh[n], accP[m][n], 0, 0, 0); \
        accP[m][n] = __builtin_amdgcn_mfma_f32_16x16x32_bf16(ah[m], bl[n], accP[m][n], 0, 0, 0); \
      }                                                                              \
  } while (0)

  // prologue: stage (e=0, k=0) into buffer 0
  STAGE_A(0, 0);
  STAGE_B(0, 0, 0);
  __syncthreads();

#pragma unroll 1
  for (int e = 0; e < EXPERTS; ++e) {
#pragma unroll 1
    for (int ks = 0; ks < 16; ks += 2) {
      // substep 0: compute buf0 tile (e, ks); stage (e, ks+1) -> buf1
      STAGE_A((ks + 1) * 32, 1);
      STAGE_B(e, (ks + 1) * 32, 1);
      COMPUTE(0);
      __syncthreads();   // vmcnt drained after ~48 MFMAs -> latency covered

      // substep 1: compute buf1 tile (e, ks+1); stage next -> buf0
      if (ks + 2 < 16) {
        STAGE_A((ks + 2) * 32, 0);
        STAGE_B(e, (ks + 2) * 32, 0);
      } else if (e < EXPERTS - 1) {
        STAGE_A(0, 0);
        STAGE_B(e + 1, 0, 0);
      }
      COMPUTE(1);
      __syncthreads();
    }

    // per-expert fold: accY += g[row,e] * accP; accP -> 0.  (accP is otherwise
    // only MFMA-chained, so it can live in AGPRs; this runs once per 16 k-steps.)
#pragma unroll
    for (int m = 0; m < 4; ++m) {
      const f32x4 gv = *(const f32x4*)(sGateT + e * 128 + wr * 64 + m * 16 + l4 * 4);
#pragma unroll
      for (int n = 0; n < 4; ++n) {
#pragma unroll
        for (int j = 0; j < 4; ++j) accY[m][n][j] += gv[j] * accP[m][n][j];
        accP[m][n] = (f32x4){0.f, 0.f, 0.f, 0.f};
      }
    }
  }

  // epilogue: y += sum_e g[row,e] * bias[e,col]; then store
#pragma unroll 1
  for (int e = 0; e < EXPERTS; ++e) {
    f32x4 gm[4];
#pragma unroll
    for (int m = 0; m < 4; ++m)
      gm[m] = *(const f32x4*)(sGateT + e * 128 + wr * 64 + m * 16 + l4 * 4);
#pragma unroll
    for (int n = 0; n < 4; ++n) {
      const float bb = bias[(size_t)e * OUT_DIM + bcol + wc * 64 + n * 16 + l15];
#pragma unroll
      for (int m = 0; m < 4; ++m)
#pragma unroll
        for (int j = 0; j < 4; ++j) accY[m][n][j] += gm[m][j] * bb;
    }
  }

#pragma unroll
  for (int m = 0; m < 4; ++m)
#pragma unroll
    for (int n = 0; n < 4; ++n) {
      const int row = brow + wr * 64 + m * 16 + l4 * 4;
      const int col = bcol + wc * 64 + n * 16 + l15;
#pragma unroll
      for (int j = 0; j < 4; ++j)
        out[(size_t)(row + j) * OUT_DIM + col] = accY[m][n][j];
    }
#undef STAGE_A
#undef STAGE_B
#undef COMPUTE
}

extern "C" void kernel_launch(void* const* d_in, const int* in_sizes, int n_in,
                              void* d_out, int out_size, void* d_ws, size_t ws_size,
                              hipStream_t stream) {
  const float* x     = (const float*)d_in[0];  // [B][I]
  const float* gates = (const float*)d_in[1];  // [B][E]
  const float* W     = (const float*)d_in[2];  // [E][I][O]
  const float* bias  = (const float*)d_in[3];  // [E][1][O]
  float* out = (float*)d_out;

  // workspace layout: Wt_hi(4MiB) | Wt_lo(4MiB) | Xh(64MiB) | Xl(64MiB) = 136MiB
  unsigned short* Wth = (unsigned short*)d_ws;
  unsigned short* Wtl = Wth + (size_t)EXPERTS * IN_DIM * OUT_DIM;
  unsigned short* Xh  = Wtl + (size_t)EXPERTS * IN_DIM * OUT_DIM;
  unsigned short* Xl  = Xh + (size_t)BATCH * IN_DIM;

  wsplit_kernel<<<dim3(16, 16, 8), 256, 0, stream>>>(W, Wth, Wtl);
  xsplit_kernel<<<dim3(BATCH * IN_DIM / 4 / 256), 256, 0, stream>>>(x, Xh, Xl);
  // row-fast grid: consecutive blocks share the same 2MB W col-panel (L2-resident)
  moe_gemm_kernel<<<dim3(BATCH / 128, OUT_DIM / 128), 256, 0, stream>>>(
      Xh, Xl, Wth, Wtl, gates, bias, out);
}

// Round 6
// 1047.909 us; speedup vs baseline: 7.2949x; 1.0691x over previous
//
#include <hip/hip_runtime.h>
#include <hip/hip_bf16.h>
#include <cstdint>

#define BATCH 65536
#define EXPERTS 8
#define IN_DIM 512
#define OUT_DIM 512

typedef short bf16x8 __attribute__((ext_vector_type(8)));
typedef float f32x4 __attribute__((ext_vector_type(4)));
typedef float f32x16 __attribute__((ext_vector_type(16)));

__device__ __forceinline__ unsigned short f2bf_rne(float f) {
  unsigned u = __float_as_uint(f);
  u += 0x7FFFu + ((u >> 16) & 1u);   // round-to-nearest-even (inputs finite)
  return (unsigned short)(u >> 16);
}
__device__ __forceinline__ float bf2f(unsigned short h) {
  return __uint_as_float(((unsigned)h) << 16);
}

// async global->LDS, 16B per lane; LDS dest is wave-uniform base + lane*16 (guide §5)
__device__ __forceinline__ void async_copy16(void* lds, const void* g) {
  __builtin_amdgcn_global_load_lds((const __attribute__((address_space(1))) void*)g,
                                   (__attribute__((address_space(3))) void*)lds, 16, 0, 0);
}

// ---- prep 1: W [E][I][O] f32 -> Wt_hi/Wt_lo [E][O][I] bf16 (split + transpose) ----
__global__ __launch_bounds__(256) void wsplit_kernel(const float* __restrict__ W,
                                                     unsigned short* __restrict__ Wth,
                                                     unsigned short* __restrict__ Wtl) {
  __shared__ float t[32][33];
  const int e = blockIdx.z;
  const int i0 = blockIdx.x * 32;
  const int o0 = blockIdx.y * 32;
  const int tx = threadIdx.x & 31, ty = threadIdx.x >> 5;  // 32x8
#pragma unroll
  for (int p = 0; p < 4; ++p)
    t[ty + p * 8][tx] = W[(size_t)(e * IN_DIM + i0 + ty + p * 8) * OUT_DIM + o0 + tx];
  __syncthreads();
#pragma unroll
  for (int p = 0; p < 4; ++p) {
    float v = t[tx][ty + p * 8];                 // v = W[e][i0+tx][o0+ty+p*8]
    unsigned short hi = f2bf_rne(v);
    unsigned short lo = f2bf_rne(v - bf2f(hi));
    size_t idx = (size_t)(e * OUT_DIM + o0 + ty + p * 8) * IN_DIM + i0 + tx;
    Wth[idx] = hi;
    Wtl[idx] = lo;
  }
}

// ---- prep 2: x [B][I] f32 -> Xh/Xl bf16 ----
__global__ __launch_bounds__(256) void xsplit_kernel(const float* __restrict__ x,
                                                     unsigned short* __restrict__ Xh,
                                                     unsigned short* __restrict__ Xl) {
  const size_t i4 = (size_t)blockIdx.x * 256 + threadIdx.x;
  const float4 v = ((const float4*)x)[i4];
  ushort4 h, l;
  h.x = f2bf_rne(v.x); l.x = f2bf_rne(v.x - bf2f(h.x));
  h.y = f2bf_rne(v.y); l.y = f2bf_rne(v.y - bf2f(h.y));
  h.z = f2bf_rne(v.z); l.z = f2bf_rne(v.z - bf2f(h.z));
  h.w = f2bf_rne(v.w); l.w = f2bf_rne(v.w - bf2f(h.w));
  ((ushort4*)Xh)[i4] = h;
  ((ushort4*)Xl)[i4] = l;
}

// ---- main GEMM: 128x128 tile, BK=32, 4 waves (2x2), 32x32x16 bf16 MFMA x3 passes.
//      R1 rhythm (stage -> sync -> compute -> sync; single buffer): compiler alias
//      conservatism makes stage-early a loss at HIP level (R5 post-mortem).
//      Expert-OUTER, accP MFMA-chained only (AGPR, fold once/expert; R4 lesson).
//      XOR swizzle slot = c ^ (row&3) ^ ((row>>2)&3): rows 0-7 cover all 32 banks. ----
__global__ __launch_bounds__(256, 2) void moe_gemm_kernel(
    const unsigned short* __restrict__ Xh, const unsigned short* __restrict__ Xl,
    const unsigned short* __restrict__ Wth, const unsigned short* __restrict__ Wtl,
    const float* __restrict__ gates,   // [B][E]
    const float* __restrict__ bias,    // [E][O]
    float* __restrict__ out) {         // [B][O]
  __shared__ __align__(16) unsigned short sAh[4096], sAl[4096];   // 16 KB
  __shared__ __align__(16) unsigned short sBh[4096], sBl[4096];   // 16 KB
  __shared__ __align__(16) float sGateT[EXPERTS * 128];           // 4 KB

  const int tid = threadIdx.x;
  const int lane = tid & 63;
  const int wid = tid >> 6;
  const int wr = wid >> 1, wc = wid & 1;
  const int l31 = lane & 31, lhi = lane >> 5;

  const int bcol = blockIdx.x * 128;   // output-feature tile (4, fast dim — R1 grid)
  const int brow = blockIdx.y * 128;   // batch tile (512, slow dim)

  // gates -> LDS transposed [e][row] for float4 reads in the per-expert fold
  {
    const int r = tid >> 1, q = (tid & 1) * 4;
    float4 g4 = *(const float4*)(gates + (size_t)(brow + r) * EXPERTS + q);
    sGateT[(q + 0) * 128 + r] = g4.x;
    sGateT[(q + 1) * 128 + r] = g4.y;
    sGateT[(q + 2) * 128 + r] = g4.z;
    sGateT[(q + 3) * 128 + r] = g4.w;
  }

  // staging: thread t -> LDS row (t>>2), linear slot (t&3); the GLOBAL chunk
  // fetched is the inverse-swizzled one so ds_reads below are conflict-free.
  const int srow = tid >> 2;                                            // 0..63
  const int csel = ((tid & 3) ^ (srow & 3) ^ ((srow >> 2) & 3)) * 8;    // elem offset
  const unsigned short* gAh = Xh + (size_t)(brow + srow) * IN_DIM + csel;
  const unsigned short* gAl = Xl + (size_t)(brow + srow) * IN_DIM + csel;
  const unsigned short* gBh = Wth + (size_t)(bcol + srow) * IN_DIM + csel;
  const unsigned short* gBl = Wtl + (size_t)(bcol + srow) * IN_DIM + csel;
  const int wb = wid * 1024;  // per-wave byte base within a 4KB half-plane

#define STAGE(e, kk)                                                               \
  do {                                                                             \
    const size_t eo = (size_t)(e) * OUT_DIM * IN_DIM;                              \
    async_copy16((char*)sAh + wb,        gAh + (kk));                              \
    async_copy16((char*)sAh + 4096 + wb, gAh + (kk) + 64 * IN_DIM);                \
    async_copy16((char*)sAl + wb,        gAl + (kk));                              \
    async_copy16((char*)sAl + 4096 + wb, gAl + (kk) + 64 * IN_DIM);                \
    async_copy16((char*)sBh + wb,        gBh + eo + (kk));                         \
    async_copy16((char*)sBh + 4096 + wb, gBh + eo + (kk) + 64 * IN_DIM);           \
    async_copy16((char*)sBl + wb,        gBl + eo + (kk));                         \
    async_copy16((char*)sBl + 4096 + wb, gBl + eo + (kk) + 64 * IN_DIM);           \
  } while (0)

  // swizzled fragment read offsets (elements): chunk = ks*2 + (lane>>5);
  // slot = chunk ^ (row&3) ^ ((row>>2)&3)
  int aoff[2][2], boff[2][2];
#pragma unroll
  for (int m = 0; m < 2; ++m) {
    const int row = wr * 64 + m * 32 + l31;
#pragma unroll
    for (int ks = 0; ks < 2; ++ks) {
      const int c = ks * 2 + lhi;
      aoff[m][ks] = row * 32 + ((c ^ (row & 3) ^ ((row >> 2) & 3)) * 8);
    }
  }
#pragma unroll
  for (int n = 0; n < 2; ++n) {
    const int row = wc * 64 + n * 32 + l31;
#pragma unroll
    for (int ks = 0; ks < 2; ++ks) {
      const int c = ks * 2 + lhi;
      boff[n][ks] = row * 32 + ((c ^ (row & 3) ^ ((row >> 2) & 3)) * 8);
    }
  }

  f32x16 accY[2][2], accP[2][2];
#pragma unroll
  for (int m = 0; m < 2; ++m)
#pragma unroll
    for (int n = 0; n < 2; ++n)
#pragma unroll
      for (int j = 0; j < 16; ++j) { accY[m][n][j] = 0.f; accP[m][n][j] = 0.f; }

#pragma unroll 1
  for (int e = 0; e < EXPERTS; ++e) {
#pragma unroll 1
    for (int kk = 0; kk < IN_DIM; kk += 32) {
      STAGE(e, kk);
      __syncthreads();   // single drain point (m97 rhythm)

      bf16x8 ah[2][2], al[2][2], bh[2][2], bl[2][2];
#pragma unroll
      for (int m = 0; m < 2; ++m)
#pragma unroll
        for (int ks = 0; ks < 2; ++ks) {
          ah[m][ks] = *(const bf16x8*)(sAh + aoff[m][ks]);
          al[m][ks] = *(const bf16x8*)(sAl + aoff[m][ks]);
        }
#pragma unroll
      for (int n = 0; n < 2; ++n)
#pragma unroll
        for (int ks = 0; ks < 2; ++ks) {
          bh[n][ks] = *(const bf16x8*)(sBh + boff[n][ks]);
          bl[n][ks] = *(const bf16x8*)(sBl + boff[n][ks]);
        }

#pragma unroll
      for (int ks = 0; ks < 2; ++ks)
#pragma unroll
        for (int m = 0; m < 2; ++m)
#pragma unroll
          for (int n = 0; n < 2; ++n) {
            accP[m][n] = __builtin_amdgcn_mfma_f32_32x32x16_bf16(ah[m][ks], bh[n][ks], accP[m][n], 0, 0, 0);
            accP[m][n] = __builtin_amdgcn_mfma_f32_32x32x16_bf16(al[m][ks], bh[n][ks], accP[m][n], 0, 0, 0);
            accP[m][n] = __builtin_amdgcn_mfma_f32_32x32x16_bf16(ah[m][ks], bl[n][ks], accP[m][n], 0, 0, 0);
          }
      __syncthreads();   // WAR fence before next stage overwrites the buffers
    }

    // per-expert fold: accY += g[row,e] * accP; accP -> 0.
    // C/D row = (reg&3) + 8*(reg>>2) + 4*(lane>>5)  [m74/m101]
#pragma unroll
    for (int m = 0; m < 2; ++m)
#pragma unroll
      for (int rq = 0; rq < 4; ++rq) {
        const f32x4 gv = *(const f32x4*)(sGateT + e * 128 + wr * 64 + m * 32 + rq * 8 + 4 * lhi);
#pragma unroll
        for (int n = 0; n < 2; ++n)
#pragma unroll
          for (int j = 0; j < 4; ++j) {
            accY[m][n][rq * 4 + j] += gv[j] * accP[m][n][rq * 4 + j];
            accP[m][n][rq * 4 + j] = 0.f;
          }
      }
  }

  // epilogue: y += sum_e g[row,e] * bias[e,col]; then store
#pragma unroll 1
  for (int e = 0; e < EXPERTS; ++e) {
    f32x4 gm[2][4];
#pragma unroll
    for (int m = 0; m < 2; ++m)
#pragma unroll
      for (int rq = 0; rq < 4; ++rq)
        gm[m][rq] = *(const f32x4*)(sGateT + e * 128 + wr * 64 + m * 32 + rq * 8 + 4 * lhi);
#pragma unroll
    for (int n = 0; n < 2; ++n) {
      const float bb = bias[(size_t)e * OUT_DIM + bcol + wc * 64 + n * 32 + l31];
#pragma unroll
      for (int m = 0; m < 2; ++m)
#pragma unroll
        for (int rq = 0; rq < 4; ++rq)
#pragma unroll
          for (int j = 0; j < 4; ++j) accY[m][n][rq * 4 + j] += gm[m][rq][j] * bb;
    }
  }

#pragma unroll
  for (int m = 0; m < 2; ++m)
#pragma unroll
    for (int n = 0; n < 2; ++n) {
      const int col = bcol + wc * 64 + n * 32 + l31;
#pragma unroll
      for (int rq = 0; rq < 4; ++rq) {
        const int row0 = brow + wr * 64 + m * 32 + rq * 8 + 4 * lhi;
#pragma unroll
        for (int j = 0; j < 4; ++j)
          out[(size_t)(row0 + j) * OUT_DIM + col] = accY[m][n][rq * 4 + j];
      }
    }
#undef STAGE
}

extern "C" void kernel_launch(void* const* d_in, const int* in_sizes, int n_in,
                              void* d_out, int out_size, void* d_ws, size_t ws_size,
                              hipStream_t stream) {
  const float* x     = (const float*)d_in[0];  // [B][I]
  const float* gates = (const float*)d_in[1];  // [B][E]
  const float* W     = (const float*)d_in[2];  // [E][I][O]
  const float* bias  = (const float*)d_in[3];  // [E][1][O]
  float* out = (float*)d_out;

  // workspace layout: Wt_hi(4MiB) | Wt_lo(4MiB) | Xh(64MiB) | Xl(64MiB) = 136MiB
  unsigned short* Wth = (unsigned short*)d_ws;
  unsigned short* Wtl = Wth + (size_t)EXPERTS * IN_DIM * OUT_DIM;
  unsigned short* Xh  = Wtl + (size_t)EXPERTS * IN_DIM * OUT_DIM;
  unsigned short* Xl  = Xh + (size_t)BATCH * IN_DIM;

  wsplit_kernel<<<dim3(16, 16, 8), 256, 0, stream>>>(W, Wth, Wtl);
  xsplit_kernel<<<dim3(BATCH * IN_DIM / 4 / 256), 256, 0, stream>>>(x, Xh, Xl);
  // R1 grid: col-fast (matches the 862 us baseline regime)
  moe_gemm_kernel<<<dim3(OUT_DIM / 128, BATCH / 128), 256, 0, stream>>>(
      Xh, Xl, Wth, Wtl, gates, bias, out);
}